// Round 1
// baseline (6388.145 us; speedup 1.0000x reference)
//
#include <hip/hip_runtime.h>
#include <hip/hip_bf16.h>
#include <stdint.h>

// Persistent-RNN design:
//  - 256 blocks (1/CU), 256 threads (4 waves). 8 batch-groups x 32 blocks.
//  - Block (g,m): batch rows [16g,16g+16), hidden cols [32m,32m+32).
//  - W_hh/W_ih held as bf16 hi+lo MFMA B-fragments in REGISTERS for all 512 steps.
//  - Per step: x-part MFMAs (overlaps sync), poll group counter, acquire fence,
//    load packed state from IC, 3-product bf16x2 MFMAs, LDS cross-wave K-reduce,
//    tanh (fp32), store packed state, release fence, atomicAdd counter.
//  - State: double-buffered [2][128][1024] u32 = (bf16hi<<16)|bf16lo in d_ws.

#define TSTEPS 512
#define BATCH  128
#define NI     256
#define NH     1024
#define NO     128
#define GROUPS 8
#define CPG    32
#define BG     16
#define COLS   32

typedef __attribute__((ext_vector_type(8))) short s16x8;
typedef __attribute__((ext_vector_type(4))) float f32x4;

__device__ __forceinline__ unsigned short f2bf_rne(float f) {
  unsigned u = __builtin_bit_cast(unsigned, f);
  unsigned r = u + 0x7fffu + ((u >> 16) & 1u);
  return (unsigned short)(r >> 16);
}
__device__ __forceinline__ float bf2f(unsigned short h) {
  unsigned u = ((unsigned)h) << 16;
  return __builtin_bit_cast(float, u);
}
__device__ __forceinline__ void split_bf(float v, short &hi, short &lo) {
  unsigned short h = f2bf_rne(v);
  hi = (short)h;
  lo = (short)f2bf_rne(v - bf2f(h));
}
__device__ __forceinline__ f32x4 mfma16(s16x8 a, s16x8 b, f32x4 c) {
  return __builtin_amdgcn_mfma_f32_16x16x32_bf16(a, b, c, 0, 0, 0);
}
__device__ __forceinline__ float fast_tanh(float a) {
  float cl = fminf(fmaxf(a, -15.f), 15.f);
  float e  = __expf(2.f * cl);
  return (e - 1.f) / (e + 1.f);
}

__global__ __launch_bounds__(256, 1)
void rnn_persistent(const float* __restrict__ x,
                    const float* __restrict__ W_ih,
                    const float* __restrict__ W_hh,
                    const float* __restrict__ b_ih,
                    const float* __restrict__ b_hh,
                    unsigned*    __restrict__ state,   // [2][128][1024] packed
                    unsigned*    __restrict__ flags)   // [8][32] (slot 0 per group = counter)
{
  const int tid  = threadIdx.x;
  const int wave = tid >> 6;
  const int lane = tid & 63;
  const int lr   = lane & 15;   // row (A/m) or col (B/n) within tile
  const int lq   = lane >> 4;   // quad
  const int g    = blockIdx.x >> 5;
  const int m    = blockIdx.x & 31;
  const int row0 = g * BG;
  const int h0   = m * COLS;

  __shared__ float red[4][512];

  // ---- persistent W_hh B-fragments: wave's K-quarter, 2 n-tiles, hi/lo ----
  // B[k][n] = W_hh[h0+n][k]; lane holds k = quad*8+j, n = lane&15.
  s16x8 whh_hi[2][8], whh_lo[2][8];
  const int kq0 = wave * 256;
  #pragma unroll
  for (int nt = 0; nt < 2; ++nt) {
    const int h = h0 + nt * 16 + lr;
    #pragma unroll
    for (int kb = 0; kb < 8; ++kb) {
      const float* p = W_hh + (size_t)h * NH + kq0 + kb * 32 + lq * 8;
      s16x8 hi, lo;
      #pragma unroll
      for (int j = 0; j < 8; ++j) { short a, b; split_bf(p[j], a, b); hi[j] = a; lo[j] = b; }
      whh_hi[nt][kb] = hi; whh_lo[nt][kb] = lo;
    }
  }
  // ---- persistent W_ih B-fragments: wave's 64-wide input K-slice ----
  s16x8 wih_hi[2][2], wih_lo[2][2];
  const int iq0 = wave * 64;
  #pragma unroll
  for (int nt = 0; nt < 2; ++nt) {
    const int h = h0 + nt * 16 + lr;
    #pragma unroll
    for (int kb = 0; kb < 2; ++kb) {
      const float* p = W_ih + (size_t)h * NI + iq0 + kb * 32 + lq * 8;
      s16x8 hi, lo;
      #pragma unroll
      for (int j = 0; j < 8; ++j) { short a, b; split_bf(p[j], a, b); hi[j] = a; lo[j] = b; }
      wih_hi[nt][kb] = hi; wih_lo[nt][kb] = lo;
    }
  }

  const int   cc   = tid & 31;                       // column this thread reduces
  const float bias = b_ih[h0 + cc] + b_hh[h0 + cc];

  unsigned* buf0 = state;
  unsigned* buf1 = state + BATCH * NH;
  unsigned* cnt  = flags + g * CPG;                  // group counter (slot 0)

  for (int t = 0; t < TSTEPS; ++t) {
    // ---------- input-projection part (independent of state; overlaps sync) ----------
    f32x4 acc0 = {0.f, 0.f, 0.f, 0.f}, acc1 = {0.f, 0.f, 0.f, 0.f};
    {
      const float* xp = x + (size_t)t * BATCH * NI + (size_t)(row0 + lr) * NI + iq0 + lq * 8;
      #pragma unroll
      for (int kb = 0; kb < 2; ++kb) {
        s16x8 xhi, xlo;
        #pragma unroll
        for (int j = 0; j < 8; ++j) { short a, b; split_bf(xp[kb * 32 + j], a, b); xhi[j] = a; xlo[j] = b; }
        acc0 = mfma16(xhi, wih_hi[0][kb], acc0);
        acc0 = mfma16(xhi, wih_lo[0][kb], acc0);
        acc0 = mfma16(xlo, wih_hi[0][kb], acc0);
        acc1 = mfma16(xhi, wih_hi[1][kb], acc1);
        acc1 = mfma16(xhi, wih_lo[1][kb], acc1);
        acc1 = mfma16(xlo, wih_hi[1][kb], acc1);
      }
    }
    // ---------- wait until state for step t is complete (all 32 members) ----------
    if (t > 0) {
      if (wave == 0) {
        if (lane == 0) {
          const unsigned target = 32u * (unsigned)t;
          while (__hip_atomic_load(cnt, __ATOMIC_RELAXED, __HIP_MEMORY_SCOPE_AGENT) < target) { }
        }
        __builtin_amdgcn_fence(__ATOMIC_ACQUIRE, "agent");   // invalidate L1/L2 -> read fresh from IC
      }
      __syncthreads();
    }
    // ---------- recurrent part: A = state rows, B = W_hh fragments ----------
    const unsigned* sb = (t & 1 ? buf1 : buf0) + (size_t)(row0 + lr) * NH + kq0 + lq * 8;
    #pragma unroll
    for (int kb = 0; kb < 8; ++kb) {
      uint4 pa = *(const uint4*)(sb + kb * 32);
      uint4 pb = *(const uint4*)(sb + kb * 32 + 4);
      s16x8 shi, slo;
      shi[0] = (short)(pa.x >> 16); slo[0] = (short)(pa.x & 0xffffu);
      shi[1] = (short)(pa.y >> 16); slo[1] = (short)(pa.y & 0xffffu);
      shi[2] = (short)(pa.z >> 16); slo[2] = (short)(pa.z & 0xffffu);
      shi[3] = (short)(pa.w >> 16); slo[3] = (short)(pa.w & 0xffffu);
      shi[4] = (short)(pb.x >> 16); slo[4] = (short)(pb.x & 0xffffu);
      shi[5] = (short)(pb.y >> 16); slo[5] = (short)(pb.y & 0xffffu);
      shi[6] = (short)(pb.z >> 16); slo[6] = (short)(pb.z & 0xffffu);
      shi[7] = (short)(pb.w >> 16); slo[7] = (short)(pb.w & 0xffffu);
      acc0 = mfma16(shi, whh_hi[0][kb], acc0);
      acc0 = mfma16(shi, whh_lo[0][kb], acc0);
      acc0 = mfma16(slo, whh_hi[0][kb], acc0);
      acc1 = mfma16(shi, whh_hi[1][kb], acc1);
      acc1 = mfma16(shi, whh_lo[1][kb], acc1);
      acc1 = mfma16(slo, whh_hi[1][kb], acc1);
    }
    // ---------- cross-wave K reduction in LDS ----------
    // C/D layout: col = lane&15, row = quad*4 + reg  (m89/m91 verified)
    #pragma unroll
    for (int r = 0; r < 4; ++r) {
      red[wave][(lq * 4 + r) * 32 + lr]      = acc0[r];
      red[wave][(lq * 4 + r) * 32 + 16 + lr] = acc1[r];
    }
    __syncthreads();
    unsigned* ob = ((t + 1) & 1) ? buf1 : buf0;
    #pragma unroll
    for (int e = tid; e < 512; e += 256) {
      float s  = red[0][e] + red[1][e] + red[2][e] + red[3][e] + bias;
      float th = fast_tanh(s);
      unsigned short hh = f2bf_rne(th);
      unsigned short ll = f2bf_rne(th - bf2f(hh));
      const int r = e >> 5;   // e = r*32 + c, c == cc for both iterations
      ob[(size_t)(row0 + r) * NH + h0 + cc] = ((unsigned)hh << 16) | (unsigned)ll;
    }
    __syncthreads();          // drains all waves' stores (vmcnt 0) + protects red[]
    if (tid == 0) {
      __builtin_amdgcn_fence(__ATOMIC_RELEASE, "agent");     // wbl2: flush stores to IC
      __hip_atomic_fetch_add(cnt, 1u, __ATOMIC_RELAXED, __HIP_MEMORY_SCOPE_AGENT);
    }
  }
}

__global__ __launch_bounds__(512)
void rnn_readout(const unsigned* __restrict__ state,   // final state = buf0
                 const float* __restrict__ W_ro,       // [128][1024]
                 const float* __restrict__ b_ro,       // [128]
                 float* __restrict__ out)              // [128][128]
{
  __shared__ float srow[4][NH];
  const int b0 = blockIdx.x * 4;
  for (int i = threadIdx.x; i < 4 * NH; i += 512) {
    unsigned u = state[(size_t)(b0 + (i >> 10)) * NH + (i & 1023)];
    srow[i >> 10][i & 1023] = bf2f((unsigned short)(u >> 16)) + bf2f((unsigned short)(u & 0xffffu));
  }
  __syncthreads();
  const int bb = threadIdx.x >> 7;     // 0..3
  const int o  = threadIdx.x & 127;
  const float* wr = W_ro + (size_t)o * NH;
  float s = 0.f;
  #pragma unroll 4
  for (int k = 0; k < NH; ++k) s += srow[bb][k] * wr[k];
  out[(size_t)(b0 + bb) * NO + o] = s + b_ro[o];
}

extern "C" void kernel_launch(void* const* d_in, const int* in_sizes, int n_in,
                              void* d_out, int out_size, void* d_ws, size_t ws_size,
                              hipStream_t stream) {
  (void)in_sizes; (void)n_in; (void)out_size; (void)ws_size;
  const float* x    = (const float*)d_in[0];
  const float* W_ih = (const float*)d_in[1];
  const float* W_hh = (const float*)d_in[2];
  const float* b_ih = (const float*)d_in[3];
  const float* b_hh = (const float*)d_in[4];
  const float* W_ro = (const float*)d_in[5];
  const float* b_ro = (const float*)d_in[6];
  float* out = (float*)d_out;

  unsigned* state = (unsigned*)d_ws;                   // 2*128*1024 u32 = 1 MB
  unsigned* flags = state + 2 * BATCH * NH;            // 256 u32

  hipMemsetAsync(state, 0, (size_t)BATCH * NH * sizeof(unsigned), stream);  // state_0 = 0
  hipMemsetAsync(flags, 0, (size_t)GROUPS * CPG * sizeof(unsigned), stream);

  rnn_persistent<<<GROUPS * CPG, 256, 0, stream>>>(x, W_ih, W_hh, b_ih, b_hh, state, flags);
  // T=512 even -> final state lands in buf0 (= state base)
  rnn_readout<<<BATCH / 4, 512, 0, stream>>>(state, W_ro, b_ro, out);
}

// Round 2
// 2977.524 us; speedup vs baseline: 2.1455x; 2.1455x over previous
//
#include <hip/hip_runtime.h>
#include <hip/hip_bf16.h>
#include <stdint.h>

// Persistent-RNN, R2: fence-free sync.
//  - 256 blocks (1/CU), 256 threads (4 waves). 8 batch-groups x 32 blocks.
//  - Block (g,m): batch rows [16g,16g+16), hidden cols [32m,32m+32).
//  - W_hh/W_ih held as bf16 hi+lo MFMA B-fragments in REGISTERS for all 512 steps.
//  - R1 -> R2: replaced agent-scope acquire/release fences (buffer_inv /
//    buffer_wbl2 = whole-L2 maintenance, 256 blocks x 512 steps = the 12.4us/step
//    stall) with per-access coherent relaxed agent atomics (sc-bit L2-bypass,
//    served by Infinity Cache). No cache-wide ops remain in the loop.
//  - State: double-buffered [2][128][1024] u32 = (bf16hi<<16)|bf16lo in d_ws.

#define TSTEPS 512
#define BATCH  128
#define NI     256
#define NH     1024
#define NO     128
#define GROUPS 8
#define CPG    32
#define BG     16
#define COLS   32

typedef __attribute__((ext_vector_type(8))) short s16x8;
typedef __attribute__((ext_vector_type(4))) float f32x4;

__device__ __forceinline__ unsigned short f2bf_rne(float f) {
  unsigned u = __builtin_bit_cast(unsigned, f);
  unsigned r = u + 0x7fffu + ((u >> 16) & 1u);
  return (unsigned short)(r >> 16);
}
__device__ __forceinline__ float bf2f(unsigned short h) {
  unsigned u = ((unsigned)h) << 16;
  return __builtin_bit_cast(float, u);
}
__device__ __forceinline__ void split_bf(float v, short &hi, short &lo) {
  unsigned short h = f2bf_rne(v);
  hi = (short)h;
  lo = (short)f2bf_rne(v - bf2f(h));
}
__device__ __forceinline__ f32x4 mfma16(s16x8 a, s16x8 b, f32x4 c) {
  return __builtin_amdgcn_mfma_f32_16x16x32_bf16(a, b, c, 0, 0, 0);
}
__device__ __forceinline__ float fast_tanh(float a) {
  float cl = fminf(fmaxf(a, -15.f), 15.f);
  float e  = __expf(2.f * cl);
  return (e - 1.f) / (e + 1.f);
}

__global__ __launch_bounds__(256, 1)
void rnn_persistent(const float* __restrict__ x,
                    const float* __restrict__ W_ih,
                    const float* __restrict__ W_hh,
                    const float* __restrict__ b_ih,
                    const float* __restrict__ b_hh,
                    unsigned*    __restrict__ state,   // [2][128][1024] packed
                    unsigned*    __restrict__ flags)   // [8][32] (slot 0 per group = counter)
{
  const int tid  = threadIdx.x;
  const int wave = tid >> 6;
  const int lane = tid & 63;
  const int lr   = lane & 15;   // row (A/m) or col (B/n) within tile
  const int lq   = lane >> 4;   // quad
  const int g    = blockIdx.x >> 5;
  const int m    = blockIdx.x & 31;
  const int row0 = g * BG;
  const int h0   = m * COLS;

  __shared__ float red[4][512];
  __shared__ unsigned sdep;     // polled counter value -> address dep (blocks load hoisting)

  // ---- persistent W_hh B-fragments: wave's K-quarter, 2 n-tiles, hi/lo ----
  // B[k][n] = W_hh[h0+n][k]; lane holds k = quad*8+j, n = lane&15.
  s16x8 whh_hi[2][8], whh_lo[2][8];
  const int kq0 = wave * 256;
  #pragma unroll
  for (int nt = 0; nt < 2; ++nt) {
    const int h = h0 + nt * 16 + lr;
    #pragma unroll
    for (int kb = 0; kb < 8; ++kb) {
      const float* p = W_hh + (size_t)h * NH + kq0 + kb * 32 + lq * 8;
      s16x8 hi, lo;
      #pragma unroll
      for (int j = 0; j < 8; ++j) { short a, b; split_bf(p[j], a, b); hi[j] = a; lo[j] = b; }
      whh_hi[nt][kb] = hi; whh_lo[nt][kb] = lo;
    }
  }
  // ---- persistent W_ih B-fragments: wave's 64-wide input K-slice ----
  s16x8 wih_hi[2][2], wih_lo[2][2];
  const int iq0 = wave * 64;
  #pragma unroll
  for (int nt = 0; nt < 2; ++nt) {
    const int h = h0 + nt * 16 + lr;
    #pragma unroll
    for (int kb = 0; kb < 2; ++kb) {
      const float* p = W_ih + (size_t)h * NI + iq0 + kb * 32 + lq * 8;
      s16x8 hi, lo;
      #pragma unroll
      for (int j = 0; j < 8; ++j) { short a, b; split_bf(p[j], a, b); hi[j] = a; lo[j] = b; }
      wih_hi[nt][kb] = hi; wih_lo[nt][kb] = lo;
    }
  }

  // epilogue ownership: thread j -> row j>>4, columns 2*(j&15), 2*(j&15)+1
  const int er  = tid >> 4;
  const int ec  = (tid & 15) * 2;
  const float bias0 = b_ih[h0 + ec]     + b_hh[h0 + ec];
  const float bias1 = b_ih[h0 + ec + 1] + b_hh[h0 + ec + 1];

  unsigned* buf0 = state;
  unsigned* buf1 = state + BATCH * NH;
  unsigned* cnt  = flags + g * CPG;                  // group counter (slot 0)

  if (tid == 0) sdep = 0;
  __syncthreads();

  for (int t = 0; t < TSTEPS; ++t) {
    // ---------- input-projection part (independent of state; overlaps sync) ----------
    f32x4 acc0 = {0.f, 0.f, 0.f, 0.f}, acc1 = {0.f, 0.f, 0.f, 0.f};
    {
      const float* xp = x + (size_t)t * BATCH * NI + (size_t)(row0 + lr) * NI + iq0 + lq * 8;
      #pragma unroll
      for (int kb = 0; kb < 2; ++kb) {
        s16x8 xhi, xlo;
        #pragma unroll
        for (int j = 0; j < 8; ++j) { short a, b; split_bf(xp[kb * 32 + j], a, b); xhi[j] = a; xlo[j] = b; }
        acc0 = mfma16(xhi, wih_hi[0][kb], acc0);
        acc0 = mfma16(xhi, wih_lo[0][kb], acc0);
        acc0 = mfma16(xlo, wih_hi[0][kb], acc0);
        acc1 = mfma16(xhi, wih_hi[1][kb], acc1);
        acc1 = mfma16(xhi, wih_lo[1][kb], acc1);
        acc1 = mfma16(xlo, wih_hi[1][kb], acc1);
      }
    }
    // ---------- wait until state for step t is complete (all 32 group members) ----------
    if (t > 0) {
      if (wave == 0 && lane == 0) {
        const unsigned target = 32u * (unsigned)t;
        unsigned v;
        do {
          v = __hip_atomic_load(cnt, __ATOMIC_RELAXED, __HIP_MEMORY_SCOPE_AGENT);
        } while (v < target);
        sdep = v;
      }
      __syncthreads();
    }
    const unsigned dep = sdep >> 20;   // always 0 (max counter 16384); forces data dep
    // ---------- load this wave's state K-quarter via IC-coherent atomics ----------
    const unsigned long long* sb = (const unsigned long long*)
        ((t & 1 ? buf1 : buf0) + (size_t)(row0 + lr) * NH + kq0 + lq * 8 + dep);
    unsigned long long sv[32];
    #pragma unroll
    for (int i = 0; i < 32; ++i)
      sv[i] = __hip_atomic_load(sb + (i >> 2) * 16 + (i & 3),
                                __ATOMIC_RELAXED, __HIP_MEMORY_SCOPE_AGENT);
    // ---------- recurrent MFMAs: A = state rows, B = W_hh fragments ----------
    #pragma unroll
    for (int kb = 0; kb < 8; ++kb) {
      s16x8 shi, slo;
      #pragma unroll
      for (int p = 0; p < 4; ++p) {
        unsigned long long v = sv[kb * 4 + p];
        unsigned lo32 = (unsigned)v, hi32 = (unsigned)(v >> 32);
        shi[p * 2]     = (short)(lo32 >> 16); slo[p * 2]     = (short)(lo32 & 0xffffu);
        shi[p * 2 + 1] = (short)(hi32 >> 16); slo[p * 2 + 1] = (short)(hi32 & 0xffffu);
      }
      acc0 = mfma16(shi, whh_hi[0][kb], acc0);
      acc0 = mfma16(shi, whh_lo[0][kb], acc0);
      acc0 = mfma16(slo, whh_hi[0][kb], acc0);
      acc1 = mfma16(shi, whh_hi[1][kb], acc1);
      acc1 = mfma16(shi, whh_lo[1][kb], acc1);
      acc1 = mfma16(slo, whh_hi[1][kb], acc1);
    }
    // ---------- cross-wave K reduction in LDS ----------
    // C/D layout: col = lane&15, row = quad*4 + reg  (m89/m91 verified)
    #pragma unroll
    for (int r = 0; r < 4; ++r) {
      red[wave][(lq * 4 + r) * 32 + lr]      = acc0[r];
      red[wave][(lq * 4 + r) * 32 + 16 + lr] = acc1[r];
    }
    __syncthreads();
    unsigned* ob = ((t + 1) & 1) ? buf1 : buf0;
    {
      const int e0 = er * 32 + ec;
      float s0 = red[0][e0] + red[1][e0] + red[2][e0] + red[3][e0] + bias0;
      float s1 = red[0][e0 + 1] + red[1][e0 + 1] + red[2][e0 + 1] + red[3][e0 + 1] + bias1;
      float t0 = fast_tanh(s0), t1 = fast_tanh(s1);
      unsigned short h0b = f2bf_rne(t0);
      unsigned short l0b = f2bf_rne(t0 - bf2f(h0b));
      unsigned short h1b = f2bf_rne(t1);
      unsigned short l1b = f2bf_rne(t1 - bf2f(h1b));
      unsigned long long pk = ((unsigned long long)(((unsigned)h1b << 16) | l1b) << 32)
                            |  (unsigned long long)(((unsigned)h0b << 16) | l0b);
      unsigned long long* op = (unsigned long long*)(ob + (size_t)(row0 + er) * NH + h0 + ec);
      __hip_atomic_store(op, pk, __ATOMIC_RELAXED, __HIP_MEMORY_SCOPE_AGENT);
    }
    __syncthreads();   // drains every wave's vmcnt(0): all sc-stores visible at IC; protects red[]
    if (tid == 0)
      __hip_atomic_fetch_add(cnt, 1u, __ATOMIC_RELAXED, __HIP_MEMORY_SCOPE_AGENT);
  }
}

__global__ __launch_bounds__(512)
void rnn_readout(const unsigned* __restrict__ state,   // final state = buf0
                 const float* __restrict__ W_ro,       // [128][1024]
                 const float* __restrict__ b_ro,       // [128]
                 float* __restrict__ out)              // [128][128]
{
  __shared__ float srow[4][NH];
  const int b0 = blockIdx.x * 4;
  for (int i = threadIdx.x; i < 4 * NH; i += 512) {
    unsigned u = state[(size_t)(b0 + (i >> 10)) * NH + (i & 1023)];
    srow[i >> 10][i & 1023] = bf2f((unsigned short)(u >> 16)) + bf2f((unsigned short)(u & 0xffffu));
  }
  __syncthreads();
  const int bb = threadIdx.x >> 7;     // 0..3
  const int o  = threadIdx.x & 127;
  const float* wr = W_ro + (size_t)o * NH;
  float s = 0.f;
  #pragma unroll 4
  for (int k = 0; k < NH; ++k) s += srow[bb][k] * wr[k];
  out[(size_t)(b0 + bb) * NO + o] = s + b_ro[o];
}

extern "C" void kernel_launch(void* const* d_in, const int* in_sizes, int n_in,
                              void* d_out, int out_size, void* d_ws, size_t ws_size,
                              hipStream_t stream) {
  (void)in_sizes; (void)n_in; (void)out_size; (void)ws_size;
  const float* x    = (const float*)d_in[0];
  const float* W_ih = (const float*)d_in[1];
  const float* W_hh = (const float*)d_in[2];
  const float* b_ih = (const float*)d_in[3];
  const float* b_hh = (const float*)d_in[4];
  const float* W_ro = (const float*)d_in[5];
  const float* b_ro = (const float*)d_in[6];
  float* out = (float*)d_out;

  unsigned* state = (unsigned*)d_ws;                   // 2*128*1024 u32 = 1 MB
  unsigned* flags = state + 2 * BATCH * NH;            // 256 u32

  hipMemsetAsync(state, 0, (size_t)BATCH * NH * sizeof(unsigned), stream);  // state_0 = 0
  hipMemsetAsync(flags, 0, (size_t)GROUPS * CPG * sizeof(unsigned), stream);

  rnn_persistent<<<GROUPS * CPG, 256, 0, stream>>>(x, W_ih, W_hh, b_ih, b_hh, state, flags);
  // T=512 even -> final state lands in buf0 (= state base)
  rnn_readout<<<BATCH / 4, 512, 0, stream>>>(state, W_ro, b_ro, out);
}